// Round 21
// baseline (736.066 us; speedup 1.0000x reference)
//
#include <hip/hip_runtime.h>

// Hydra_56633438765296: two-head LoLa/CoLa jet network, fp32 (no fp32 MFMA on CDNA4;
// rank-sensitive top-6 between heads keeps everything fp32 vector math).
// R20 ledger: mlp 52.5us, VALU 36%, LDS demand ~25.6us -> latency-bound at 2 blk/CU
// (70.6KB LDS). R21: chunked H -- write/consume H in two 100-neuron chunks at
// stride 132 overlaying dead U (UH 58.4->42.2KB, block 54.3KB -> 3 blocks/CU,
// 12 waves). Same 8x7 tile, same per-wave instruction mix; +2 barriers only.
// Phase C accumulates across chunks in identical neuron order -> bit-identical.

#define BATCH 32768
#define NJ 10
#define FFDIM 200
#define OUTSTRIDE 21
#define NFEATBLK 4096

typedef float v2f __attribute__((ext_vector_type(2)));

// ---------------- features kernel: cola + lola + BN partials ----------------
template<int NIN, int NP>
__global__ __launch_bounds__(256) void feat_kernel(
    const float* __restrict__ vin,    // [B][NIN][4]
    const float* __restrict__ cola,   // [22][NIN]
    const float* __restrict__ we,     // [NP][NP]
    const float* __restrict__ wd,     // [NP][NP]
    float* __restrict__ fout,         // [B][F] row-major
    float* __restrict__ psum,         // [F][4096]
    float* __restrict__ psq)          // [F][4096]
{
    constexpr int NC = 22;
    constexpr int F  = NP * 5;
    constexpr int RB = 8;             // rows per block
    constexpr int SW = NP + 1;        // odd stride -> conflict-free i-indexed reads
    constexpr int SF = F + 8;         // 2-way max on transposed readout
    __shared__ float s_cola[NC * NIN];
    __shared__ float s_we[NP * SW];
    __shared__ float s_wd[NP * SW];
    __shared__ float4 s_x[RB][NP];
    __shared__ float s_m2[RB][NP];
    __shared__ float s_f[RB * SF];

    const int tid = threadIdx.x;
    const int blk = blockIdx.x;

    for (int k = tid; k < NC * NIN; k += 256) s_cola[k] = cola[k];
    for (int k = tid; k < NP * NP; k += 256) {
        const int i2 = k / NP, j2 = k - i2 * NP;
        s_we[i2 * SW + j2] = we[k];
        s_wd[i2 * SW + j2] = wd[k];
    }
    for (int k = tid; k < RB * NIN * 4; k += 256)
        ((float*)&s_x[0][0])[(k / (NIN * 4)) * NP * 4 + (k % (NIN * 4))] =
            vin[(size_t)blk * RB * NIN * 4 + k];
    __syncthreads();

    const int r = tid >> 5;          // row in block (8)
    const int i = tid & 31;          // particle slot

    if (i >= NIN && i < NP) {        // learned combos
        const int c = i - NIN;
        float4 x = make_float4(0.f, 0.f, 0.f, 0.f);
        #pragma unroll
        for (int j = 0; j < NIN; j++) {
            const float w = s_cola[c * NIN + j];
            const float4 xj = s_x[r][j];
            x.x += w * xj.x; x.y += w * xj.y; x.z += w * xj.z; x.w += w * xj.w;
        }
        s_x[r][i] = x;
    }
    __syncthreads();

    float m2 = 0.f, pt = 0.f;
    float4 xi = make_float4(0.f, 0.f, 0.f, 0.f);
    if (i < NP) {
        xi = s_x[r][i];
        m2 = xi.x * xi.x - xi.y * xi.y - xi.z * xi.z - xi.w * xi.w;
        pt = sqrtf(xi.y * xi.y + xi.z * xi.z);
        s_m2[r][i] = m2;
    }
    __syncthreads();
    if (i < NP) {
        float wesum = 0.f, wdsum = 0.f;
        for (int j = 0; j < NP; j++) {
            const float4 xj = s_x[r][j];                    // broadcast b128
            wesum += s_we[i * SW + j] * xj.x;               // conflict-free
            const float g = xi.x * xj.x - xi.y * xj.y - xi.z * xj.z - xi.w * xj.w;
            wdsum += s_wd[i * SW + j] * (m2 + s_m2[r][j] - 2.0f * g);
        }
        s_f[r * SF + i * 5 + 0] = m2;
        s_f[r * SF + i * 5 + 1] = pt;
        s_f[r * SF + i * 5 + 2] = xi.x;
        s_f[r * SF + i * 5 + 3] = wesum;
        s_f[r * SF + i * 5 + 4] = wdsum;
    }
    __syncthreads();

    // row-major write: fout[blk*RB + rr][c]
    for (int q = tid; q < RB * F; q += 256) {
        const int rr = q / F, c = q - rr * F;
        fout[(size_t)blk * RB * F + q] = s_f[rr * SF + c];
    }

    if (tid < F) {                   // per-block BN partials (deterministic)
        float s = 0.f, s2 = 0.f;
        #pragma unroll
        for (int rr = 0; rr < RB; rr++) {
            const float v = s_f[rr * SF + tid];
            s += v; s2 += v * v;
        }
        psum[(size_t)tid * NFEATBLK + blk] = s;
        psq [(size_t)tid * NFEATBLK + blk] = s2;
    }
}

// ---------------- BN reduce: partials -> per-feature scale/shift ----------------
template<int F>
__global__ __launch_bounds__(256) void bn_reduce(
    const float* __restrict__ psum, const float* __restrict__ psq,
    const float* __restrict__ gamma, const float* __restrict__ beta,
    float* __restrict__ bn)          // [2*F]: scale then shift
{
    __shared__ float s1[256], s2[256];
    const int f = blockIdx.x, tid = threadIdx.x;
    float a = 0.f, b = 0.f;
    for (int bk = tid; bk < NFEATBLK; bk += 256) {
        a += psum[(size_t)f * NFEATBLK + bk];
        b += psq [(size_t)f * NFEATBLK + bk];
    }
    s1[tid] = a; s2[tid] = b; __syncthreads();
    for (int s = 128; s > 0; s >>= 1) {
        if (tid < s) { s1[tid] += s1[tid + s]; s2[tid] += s2[tid + s]; }
        __syncthreads();
    }
    if (tid == 0) {
        const float mu  = s1[0] / (float)BATCH;
        const float var = s2[0] / (float)BATCH - mu * mu;
        const float sc  = gamma[f] * rsqrtf(var + 1e-5f);
        bn[f]     = sc;
        bn[F + f] = beta[f] - mu * sc;
    }
}

// ---------------- MLP kernel: BN affine + FC1(relu) + FC2 (+ top-6 select) ----------------
// RB=64 rows. Thread = 8 rows x 7 neurons (rg=tid&7, ng=tid>>3).
// U[row][c] at UH[row*160 + (c ^ ((row>>3)*4))].
// H stored in TWO 100-neuron chunks at stride 132 (>=128 XOR window, ==4 mod 32),
// overlaying dead U: UH[row*132 + ((nn&~3)^((row>>3)*4)) + (nn&3)], nn = n - ch*100.
// Per-wave private LDS weight dbuf; fq (features) register double-buffered.
// LDS ~54.3KB -> 3 blocks/CU (12 waves; VGPR 128 allows 16).
template<int NF, int NOUT, bool SELECT>
__global__ __launch_bounds__(256, 3) void mlp_kernel(
    const float* __restrict__ fin,   // [B][NF] row-major
    const float* __restrict__ bn,    // [2*NF]
    const float* __restrict__ w1,    // [200][NF]
    const float* __restrict__ b1,    // [200]
    const float* __restrict__ w2,    // [NOUT][200]
    const float* __restrict__ b2,    // [NOUT]
    const float* __restrict__ vectors, // [B][10][4] (SELECT only)
    float* __restrict__ selout,      // [B][6][4]   (SELECT only)
    float* __restrict__ out,         // [B][21]
    int out_off)
{
    constexpr int RB  = 64;
    constexpr int SU  = 160;                       // U row stride
    constexpr int SH2 = 132;                       // chunked-H row stride
    constexpr int SO  = 13;                        // s_out stride (odd)
    constexpr int NCH = NF / 4;                    // k-chunks (40 or 35)
    __shared__ __align__(16) float UH[RB * SU + 320];   // 42.2KB: U / H-chunks + bn tail
    __shared__ __align__(16) float s_wv[4][2][56 * 4];  // per-wave weight dbuf
    __shared__ float s_out[RB * SO];
    __shared__ int   s_idx[RB * 6];

    const int tid  = threadIdx.x;
    const int blk  = blockIdx.x;
    const int lane = tid & 63;
    const int wvid = __builtin_amdgcn_readfirstlane(tid >> 6);  // wave id (uniform)
    float* s_scale = &UH[RB * SU];   // tail [10240..10560): dead after Phase A
    float* s_shift = s_scale + NF;

    // per-wave weight row for staging: wave wvid owns neuron rows wvid*56 .. +55
    const int nrow  = wvid * 56 + ((lane < 56) ? lane : 55);
    const int wrowg = (nrow < 200) ? nrow : 199;           // clamp padded rows
    const float* w1g = w1 + (size_t)wrowg * NF;

    for (int k = tid; k < NF; k += 256) { s_scale[k] = bn[k]; s_shift[k] = bn[NF + k]; }
    __syncthreads();

    // Phase A: coalesced float4 feature read, BN affine, swizzled U write.
    {
        constexpr int NF4 = NF / 4;
        const float4* fb4 = reinterpret_cast<const float4*>(fin + (size_t)blk * RB * NF);
        for (int q4 = tid; q4 < RB * NF4; q4 += 256) {
            const int row = q4 / NF4, c = (q4 - row * NF4) * 4;
            const float4 v = fb4[q4];
            float4 o;
            o.x = v.x * s_scale[c + 0] + s_shift[c + 0];
            o.y = v.y * s_scale[c + 1] + s_shift[c + 1];
            o.z = v.z * s_scale[c + 2] + s_shift[c + 2];
            o.w = v.w * s_scale[c + 3] + s_shift[c + 3];
            *reinterpret_cast<float4*>(&UH[row * SU + (c ^ ((row >> 3) * 4))]) = o;
        }
    }
    __syncthreads();                 // U ready; no block barriers until H overlay

    // FC1: acc[7 neurons][8 rows]; barrier-free k-loop, fq register-double-buffered.
    const int rg  = tid & 7;         // rowgroup: rows rg*8 .. rg*8+7
    const int ngl = lane >> 3;       // 0..7: local ngroup
    v2f acc[7][8];
    #pragma unroll
    for (int j = 0; j < 7; j++)
        #pragma unroll
        for (int i = 0; i < 8; i++) acc[j][i] = (v2f){0.f, 0.f};

#define FMA_TILE(WQ, FQ)                                                     \
    do {                                                                     \
        _Pragma("unroll")                                                    \
        for (int j = 0; j < 7; j++) {                                        \
            const v2f wlo = (v2f){WQ[j].x, WQ[j].y};                         \
            const v2f whi = (v2f){WQ[j].z, WQ[j].w};                         \
            _Pragma("unroll")                                                \
            for (int i = 0; i < 8; i++) {                                    \
                acc[j][i] += wlo * (v2f){FQ[i].x, FQ[i].y};                  \
                acc[j][i] += whi * (v2f){FQ[i].z, FQ[i].w};                  \
            }                                                                \
        }                                                                    \
    } while (0)

#define LD_WQ(WQ, BUF)                                                       \
    do { _Pragma("unroll")                                                   \
        for (int j = 0; j < 7; j++)                                          \
            WQ[j] = *reinterpret_cast<const float4*>(                        \
                &s_wv[wvid][BUF][(ngl * 7 + j) * 4]); } while (0)

#define LD_FQ(FQ, KT)                                                        \
    do { _Pragma("unroll")                                                   \
        for (int i = 0; i < 8; i++)                                          \
            FQ[i] = *reinterpret_cast<const float4*>(                        \
                &UH[(rg * 8 + i) * SU + (((KT) * 4) ^ (rg * 4))]); } while (0)

    // prologue: stage weight tile 0 -> buf0; wR = tile 1; preload fqA = features 0
    {
        const float4 w0 = *reinterpret_cast<const float4*>(w1g);
        if (lane < 56) *reinterpret_cast<float4*>(&s_wv[wvid][0][lane * 4]) = w0;
    }
    float4 wR = *reinterpret_cast<const float4*>(w1g + ((NCH > 1) ? 4 : 0));
    float4 fqA[8], fqB[8], wq[7];
    LD_FQ(fqA, 0);

    for (int kt = 0; kt + 1 < NCH; kt += 2) {
        // stage weight tile kt+1 -> buf1; prefetch wR = tile kt+2; features kt+1 -> fqB
        if (lane < 56)
            *reinterpret_cast<float4*>(&s_wv[wvid][1][lane * 4]) = wR;
        if (kt + 2 < NCH)
            wR = *reinterpret_cast<const float4*>(w1g + (kt + 2) * 4);
        LD_FQ(fqB, kt + 1);
        __builtin_amdgcn_sched_barrier(0);   // fqB loads stay above FMA(A)
        LD_WQ(wq, 0);
        FMA_TILE(wq, fqA);

        // stage weight tile kt+2 -> buf0; prefetch wR = tile kt+3; features kt+2 -> fqA
        if (kt + 2 < NCH) {
            if (lane < 56)
                *reinterpret_cast<float4*>(&s_wv[wvid][0][lane * 4]) = wR;
            if (kt + 3 < NCH)
                wR = *reinterpret_cast<const float4*>(w1g + (kt + 3) * 4);
            LD_FQ(fqA, kt + 2);
        }
        __builtin_amdgcn_sched_barrier(0);   // fqA loads stay above FMA(B)
        LD_WQ(wq, 1);
        FMA_TILE(wq, fqB);
    }
    if (NCH & 1) {                   // odd NCH (NF=140): last (even) tile in fqA/buf0
        LD_WQ(wq, 0);
        FMA_TILE(wq, fqA);
    }
#undef FMA_TILE
#undef LD_WQ
#undef LD_FQ
    __syncthreads();                 // all waves done reading U -> overlay H chunks

    // Chunked H + Phase C: two 100-neuron chunks; a2 accumulates across chunks in
    // the same neuron order as the monolithic version (bit-identical sums).
    const int ng = tid >> 3;
    const int r  = lane;
    const int rx = (r >> 3) * 4;     // lane-varying XOR key
    v2f a2[3];
    #pragma unroll
    for (int m = 0; m < 3; m++) a2[m] = (v2f){0.f, 0.f};

    for (int ch = 0; ch < 2; ch++) {
        // H-write for chunk ch: neurons [ch*100, ch*100+100)
        #pragma unroll
        for (int j = 0; j < 7; j++) {
            const int n = ng * 7 + j;
            if (n >= ch * 100 && n < (ch + 1) * 100 && n < 200) {
                const float bb = b1[n];
                const int nn = n - ch * 100;
                const int n4 = nn & ~3, nl = nn & 3;
                #pragma unroll
                for (int i = 0; i < 8; i++) {
                    const float h = acc[j][i][0] + acc[j][i][1] + bb;
                    UH[(rg * 8 + i) * SH2 + ((n4 ^ (rg * 4)) | nl)] = h > 0.f ? h : 0.f;
                }
            }
        }
        __syncthreads();

        // Phase C partial: wave w handles outputs {w, w+4, w+8} (uniform w2 rows).
        for (int kc = 0; kc < 25; kc++) {
            const float4 hv = *reinterpret_cast<const float4*>(
                &UH[r * SH2 + ((kc * 4) ^ rx)]);
            const v2f hlo = (v2f){hv.x, hv.y}, hhi = (v2f){hv.z, hv.w};
            #pragma unroll
            for (int m = 0; m < 3; m++) {
                const int o = wvid + 4 * m;
                if (o < NOUT) {
                    const float4 w2v = *reinterpret_cast<const float4*>(
                        w2 + (size_t)o * FFDIM + ch * 100 + kc * 4);
                    a2[m] += (v2f){w2v.x, w2v.y} * hlo;
                    a2[m] += (v2f){w2v.z, w2v.w} * hhi;
                }
            }
        }
        __syncthreads();             // chunk reads done before next overwrite
    }
    #pragma unroll
    for (int m = 0; m < 3; m++) {
        const int o = wvid + 4 * m;
        if (o < NOUT) s_out[r * SO + o] = a2[m][0] + a2[m][1] + b2[o];
    }
    __syncthreads();

    if (SELECT) {
        if (tid < RB) {              // per-row top-6 (ties -> lowest index), sorted asc
            float sc[10];
            #pragma unroll
            for (int o = 0; o < 10; o++) sc[o] = s_out[tid * SO + o];
            bool used[10];
            #pragma unroll
            for (int o = 0; o < 10; o++) used[o] = false;
            int ids[6];
            for (int k = 0; k < 6; k++) {
                float m = -3.0e38f; int mi = 0;
                for (int o = 0; o < 10; o++)
                    if (!used[o] && sc[o] > m) { m = sc[o]; mi = o; }
                used[mi] = true; ids[k] = mi;
            }
            for (int a2i = 1; a2i < 6; a2i++) {  // insertion sort ascending
                const int v = ids[a2i]; int bp = a2i - 1;
                while (bp >= 0 && ids[bp] > v) { ids[bp + 1] = ids[bp]; bp--; }
                ids[bp + 1] = v;
            }
            #pragma unroll
            for (int k = 0; k < 6; k++) s_idx[tid * 6 + k] = ids[k];
        }
        __syncthreads();
        for (int q = tid; q < RB * 6; q += 256) {    // float4 gather of selected jets
            const int r2 = q / 6, j = q - r2 * 6;
            reinterpret_cast<float4*>(selout)[(size_t)blk * RB * 6 + q] =
                reinterpret_cast<const float4*>(vectors)
                    [(size_t)(blk * RB + r2) * NJ + s_idx[r2 * 6 + j]];
        }
    }

    for (int q = tid; q < RB * NOUT; q += 256) {
        const int r2 = q / NOUT, o = q - r2 * NOUT;
        out[(size_t)(blk * RB + r2) * OUTSTRIDE + out_off + o] = s_out[r2 * SO + o];
    }
}

extern "C" void kernel_launch(void* const* d_in, const int* in_sizes, int n_in,
                              void* d_out, int out_size, void* d_ws, size_t ws_size,
                              hipStream_t stream) {
    const float* vectors  = (const float*)d_in[0];
    const float* isr_cola = (const float*)d_in[1];
    const float* isr_we   = (const float*)d_in[2];
    const float* isr_wd   = (const float*)d_in[3];
    const float* isr_bn_g = (const float*)d_in[4];
    const float* isr_bn_b = (const float*)d_in[5];
    const float* isr_w1   = (const float*)d_in[6];
    const float* isr_b1   = (const float*)d_in[7];
    const float* isr_w2   = (const float*)d_in[8];
    const float* isr_b2   = (const float*)d_in[9];
    const float* dec_cola = (const float*)d_in[10];
    const float* dec_we   = (const float*)d_in[11];
    const float* dec_wd   = (const float*)d_in[12];
    const float* dec_bn_g = (const float*)d_in[13];
    const float* dec_bn_b = (const float*)d_in[14];
    const float* dec_w1   = (const float*)d_in[15];
    const float* dec_b1   = (const float*)d_in[16];
    const float* dec_w2   = (const float*)d_in[17];
    const float* dec_b2   = (const float*)d_in[18];
    float* out = (float*)d_out;
    float* ws  = (float*)d_ws;

    // workspace layout (floats); f_buf reused by both heads (~29.4 MB total)
    float* f_buf  = ws;                    // 32768*160 = 5,242,880
    float* sel    = f_buf + 5242880;       // 32768*24 = 786,432
    float* ps     = sel + 786432;          // 160*4096 = 655,360
    float* pq     = ps + 655360;           // 655,360
    float* bn_i   = pq + 655360;           // 320
    float* bn_d   = bn_i + 320;            // 280

    feat_kernel<10, 32><<<4096, 256, 0, stream>>>(vectors, isr_cola, isr_we, isr_wd,
                                                  f_buf, ps, pq);
    bn_reduce<160><<<160, 256, 0, stream>>>(ps, pq, isr_bn_g, isr_bn_b, bn_i);
    mlp_kernel<160, 10, true><<<512, 256, 0, stream>>>(f_buf, bn_i, isr_w1, isr_b1,
                                                       isr_w2, isr_b2, vectors, sel,
                                                       out, 0);
    feat_kernel<6, 28><<<4096, 256, 0, stream>>>(sel, dec_cola, dec_we, dec_wd,
                                                 f_buf, ps, pq);
    bn_reduce<140><<<140, 256, 0, stream>>>(ps, pq, dec_bn_g, dec_bn_b, bn_d);
    mlp_kernel<140, 11, false><<<512, 256, 0, stream>>>(f_buf, bn_d, dec_w1, dec_b1,
                                                        dec_w2, dec_b2, nullptr, nullptr,
                                                        out, 10);
}

// Round 22
// 145.033 us; speedup vs baseline: 5.0751x; 5.0751x over previous
//
#include <hip/hip_runtime.h>

// Hydra_56633438765296: two-head LoLa/CoLa jet network, fp32 (no fp32 MFMA on CDNA4;
// rank-sensitive top-6 between heads keeps everything fp32 vector math).
// FINAL (revert to R15/R20, best measured 145.4us). mlp: RB=64, thread = 8 rows x
// 7 neurons, XOR-swizzled U/H union LDS, per-wave weight dbuf, barrier-free k-loop,
// packed v_pk_fma_f32. Complete ledger of failed alternatives (each with diagnosed
// mechanism): deeper ILP -> spill at the allocator's 128-VGPR operating point
// (R13/R14: WRITE_SIZE 543/19MB); waves_per_eu attr -> ignored (R15-attr);
// RB=128 -> same weight-LDS instr count + fold conflicts (R16); RB=32 TLP ->
// +50% weight-LDS instrs on the bound pipe & allocator under-allocates (R17-19);
// chunked-H 3blk/CU -> acc[112] spills at the smaller budget (R21: 1.13GB scratch).
// 2 blk/CU @ 128 VGPR is the constrained optimum for this structure.

#define BATCH 32768
#define NJ 10
#define FFDIM 200
#define OUTSTRIDE 21
#define NFEATBLK 4096

typedef float v2f __attribute__((ext_vector_type(2)));

// ---------------- features kernel: cola + lola + BN partials ----------------
template<int NIN, int NP>
__global__ __launch_bounds__(256) void feat_kernel(
    const float* __restrict__ vin,    // [B][NIN][4]
    const float* __restrict__ cola,   // [22][NIN]
    const float* __restrict__ we,     // [NP][NP]
    const float* __restrict__ wd,     // [NP][NP]
    float* __restrict__ fout,         // [B][F] row-major
    float* __restrict__ psum,         // [F][4096]
    float* __restrict__ psq)          // [F][4096]
{
    constexpr int NC = 22;
    constexpr int F  = NP * 5;
    constexpr int RB = 8;             // rows per block
    constexpr int SW = NP + 1;        // odd stride -> conflict-free i-indexed reads
    constexpr int SF = F + 8;         // 2-way max on transposed readout
    __shared__ float s_cola[NC * NIN];
    __shared__ float s_we[NP * SW];
    __shared__ float s_wd[NP * SW];
    __shared__ float4 s_x[RB][NP];
    __shared__ float s_m2[RB][NP];
    __shared__ float s_f[RB * SF];

    const int tid = threadIdx.x;
    const int blk = blockIdx.x;

    for (int k = tid; k < NC * NIN; k += 256) s_cola[k] = cola[k];
    for (int k = tid; k < NP * NP; k += 256) {
        const int i2 = k / NP, j2 = k - i2 * NP;
        s_we[i2 * SW + j2] = we[k];
        s_wd[i2 * SW + j2] = wd[k];
    }
    for (int k = tid; k < RB * NIN * 4; k += 256)
        ((float*)&s_x[0][0])[(k / (NIN * 4)) * NP * 4 + (k % (NIN * 4))] =
            vin[(size_t)blk * RB * NIN * 4 + k];
    __syncthreads();

    const int r = tid >> 5;          // row in block (8)
    const int i = tid & 31;          // particle slot

    if (i >= NIN && i < NP) {        // learned combos
        const int c = i - NIN;
        float4 x = make_float4(0.f, 0.f, 0.f, 0.f);
        #pragma unroll
        for (int j = 0; j < NIN; j++) {
            const float w = s_cola[c * NIN + j];
            const float4 xj = s_x[r][j];
            x.x += w * xj.x; x.y += w * xj.y; x.z += w * xj.z; x.w += w * xj.w;
        }
        s_x[r][i] = x;
    }
    __syncthreads();

    float m2 = 0.f, pt = 0.f;
    float4 xi = make_float4(0.f, 0.f, 0.f, 0.f);
    if (i < NP) {
        xi = s_x[r][i];
        m2 = xi.x * xi.x - xi.y * xi.y - xi.z * xi.z - xi.w * xi.w;
        pt = sqrtf(xi.y * xi.y + xi.z * xi.z);
        s_m2[r][i] = m2;
    }
    __syncthreads();
    if (i < NP) {
        float wesum = 0.f, wdsum = 0.f;
        for (int j = 0; j < NP; j++) {
            const float4 xj = s_x[r][j];                    // broadcast b128
            wesum += s_we[i * SW + j] * xj.x;               // conflict-free
            const float g = xi.x * xj.x - xi.y * xj.y - xi.z * xj.z - xi.w * xj.w;
            wdsum += s_wd[i * SW + j] * (m2 + s_m2[r][j] - 2.0f * g);
        }
        s_f[r * SF + i * 5 + 0] = m2;
        s_f[r * SF + i * 5 + 1] = pt;
        s_f[r * SF + i * 5 + 2] = xi.x;
        s_f[r * SF + i * 5 + 3] = wesum;
        s_f[r * SF + i * 5 + 4] = wdsum;
    }
    __syncthreads();

    // row-major write: fout[blk*RB + rr][c]
    for (int q = tid; q < RB * F; q += 256) {
        const int rr = q / F, c = q - rr * F;
        fout[(size_t)blk * RB * F + q] = s_f[rr * SF + c];
    }

    if (tid < F) {                   // per-block BN partials (deterministic)
        float s = 0.f, s2 = 0.f;
        #pragma unroll
        for (int rr = 0; rr < RB; rr++) {
            const float v = s_f[rr * SF + tid];
            s += v; s2 += v * v;
        }
        psum[(size_t)tid * NFEATBLK + blk] = s;
        psq [(size_t)tid * NFEATBLK + blk] = s2;
    }
}

// ---------------- BN reduce: partials -> per-feature scale/shift ----------------
template<int F>
__global__ __launch_bounds__(256) void bn_reduce(
    const float* __restrict__ psum, const float* __restrict__ psq,
    const float* __restrict__ gamma, const float* __restrict__ beta,
    float* __restrict__ bn)          // [2*F]: scale then shift
{
    __shared__ float s1[256], s2[256];
    const int f = blockIdx.x, tid = threadIdx.x;
    float a = 0.f, b = 0.f;
    for (int bk = tid; bk < NFEATBLK; bk += 256) {
        a += psum[(size_t)f * NFEATBLK + bk];
        b += psq [(size_t)f * NFEATBLK + bk];
    }
    s1[tid] = a; s2[tid] = b; __syncthreads();
    for (int s = 128; s > 0; s >>= 1) {
        if (tid < s) { s1[tid] += s1[tid + s]; s2[tid] += s2[tid + s]; }
        __syncthreads();
    }
    if (tid == 0) {
        const float mu  = s1[0] / (float)BATCH;
        const float var = s2[0] / (float)BATCH - mu * mu;
        const float sc  = gamma[f] * rsqrtf(var + 1e-5f);
        bn[f]     = sc;
        bn[F + f] = beta[f] - mu * sc;
    }
}

// ---------------- MLP kernel: BN affine + FC1(relu) + FC2 (+ top-6 select) ----------------
// RB=64 rows. Thread = 8 rows x 7 neurons (rg=tid&7, ng=tid>>3).
// U[row][c] at UH[row*160 + (c ^ ((row>>3)*4))]; H[row][n] at
// UH[row*228 + ((n&~3)^((row>>3)*4)) + (n&3)]; s_out stride 13.
// Per-wave private LDS weight dbuf; fq (features) register double-buffered.
template<int NF, int NOUT, bool SELECT>
__global__ __launch_bounds__(256)
__attribute__((amdgpu_waves_per_eu(2, 2)))
void mlp_kernel(
    const float* __restrict__ fin,   // [B][NF] row-major
    const float* __restrict__ bn,    // [2*NF]
    const float* __restrict__ w1,    // [200][NF]
    const float* __restrict__ b1,    // [200]
    const float* __restrict__ w2,    // [NOUT][200]
    const float* __restrict__ b2,    // [NOUT]
    const float* __restrict__ vectors, // [B][10][4] (SELECT only)
    float* __restrict__ selout,      // [B][6][4]   (SELECT only)
    float* __restrict__ out,         // [B][21]
    int out_off)
{
    constexpr int RB  = 64;
    constexpr int SU  = 160;                       // U row stride
    constexpr int SH  = 228;                       // H row stride: ==4 mod 32
    constexpr int SO  = 13;                        // s_out stride (odd)
    constexpr int NCH = NF / 4;                    // k-chunks (40 or 35)
    __shared__ __align__(16) float UH[RB * SH];    // 57KB: U then H (union)
    __shared__ __align__(16) float s_wv[4][2][56 * 4];  // per-wave weight dbuf
    __shared__ float s_out[RB * SO];
    __shared__ int   s_idx[RB * 6];

    const int tid  = threadIdx.x;
    const int blk  = blockIdx.x;
    const int lane = tid & 63;
    const int wvid = __builtin_amdgcn_readfirstlane(tid >> 6);  // wave id (uniform)
    float* s_scale = &UH[RB * SU];   // [10240..10560): dead after Phase A
    float* s_shift = s_scale + NF;

    // per-wave weight row for staging: wave wvid owns neuron rows wvid*56 .. +55
    const int nrow  = wvid * 56 + ((lane < 56) ? lane : 55);
    const int wrowg = (nrow < 200) ? nrow : 199;           // clamp padded rows
    const float* w1g = w1 + (size_t)wrowg * NF;

    for (int k = tid; k < NF; k += 256) { s_scale[k] = bn[k]; s_shift[k] = bn[NF + k]; }
    __syncthreads();

    // Phase A: coalesced float4 feature read, BN affine, swizzled U write.
    {
        constexpr int NF4 = NF / 4;
        const float4* fb4 = reinterpret_cast<const float4*>(fin + (size_t)blk * RB * NF);
        for (int q4 = tid; q4 < RB * NF4; q4 += 256) {
            const int row = q4 / NF4, c = (q4 - row * NF4) * 4;
            const float4 v = fb4[q4];
            float4 o;
            o.x = v.x * s_scale[c + 0] + s_shift[c + 0];
            o.y = v.y * s_scale[c + 1] + s_shift[c + 1];
            o.z = v.z * s_scale[c + 2] + s_shift[c + 2];
            o.w = v.w * s_scale[c + 3] + s_shift[c + 3];
            *reinterpret_cast<float4*>(&UH[row * SU + (c ^ ((row >> 3) * 4))]) = o;
        }
    }
    __syncthreads();                 // U ready; no block barriers until H overlay

    // FC1: acc[7 neurons][8 rows]; barrier-free k-loop, fq register-double-buffered.
    const int rg  = tid & 7;         // rowgroup: rows rg*8 .. rg*8+7
    const int ngl = lane >> 3;       // 0..7: local ngroup
    v2f acc[7][8];
    #pragma unroll
    for (int j = 0; j < 7; j++)
        #pragma unroll
        for (int i = 0; i < 8; i++) acc[j][i] = (v2f){0.f, 0.f};

#define FMA_TILE(WQ, FQ)                                                     \
    do {                                                                     \
        _Pragma("unroll")                                                    \
        for (int j = 0; j < 7; j++) {                                        \
            const v2f wlo = (v2f){WQ[j].x, WQ[j].y};                         \
            const v2f whi = (v2f){WQ[j].z, WQ[j].w};                         \
            _Pragma("unroll")                                                \
            for (int i = 0; i < 8; i++) {                                    \
                acc[j][i] += wlo * (v2f){FQ[i].x, FQ[i].y};                  \
                acc[j][i] += whi * (v2f){FQ[i].z, FQ[i].w};                  \
            }                                                                \
        }                                                                    \
    } while (0)

#define LD_WQ(WQ, BUF)                                                       \
    do { _Pragma("unroll")                                                   \
        for (int j = 0; j < 7; j++)                                          \
            WQ[j] = *reinterpret_cast<const float4*>(                        \
                &s_wv[wvid][BUF][(ngl * 7 + j) * 4]); } while (0)

#define LD_FQ(FQ, KT)                                                        \
    do { _Pragma("unroll")                                                   \
        for (int i = 0; i < 8; i++)                                          \
            FQ[i] = *reinterpret_cast<const float4*>(                        \
                &UH[(rg * 8 + i) * SU + (((KT) * 4) ^ (rg * 4))]); } while (0)

    // prologue: stage weight tile 0 -> buf0; wR = tile 1; preload fqA = features 0
    {
        const float4 w0 = *reinterpret_cast<const float4*>(w1g);
        if (lane < 56) *reinterpret_cast<float4*>(&s_wv[wvid][0][lane * 4]) = w0;
    }
    float4 wR = *reinterpret_cast<const float4*>(w1g + ((NCH > 1) ? 4 : 0));
    float4 fqA[8], fqB[8], wq[7];
    LD_FQ(fqA, 0);

    for (int kt = 0; kt + 1 < NCH; kt += 2) {
        // stage weight tile kt+1 -> buf1; prefetch wR = tile kt+2; features kt+1 -> fqB
        if (lane < 56)
            *reinterpret_cast<float4*>(&s_wv[wvid][1][lane * 4]) = wR;
        if (kt + 2 < NCH)
            wR = *reinterpret_cast<const float4*>(w1g + (kt + 2) * 4);
        LD_FQ(fqB, kt + 1);
        __builtin_amdgcn_sched_barrier(0);   // fqB loads stay above FMA(A)
        LD_WQ(wq, 0);
        FMA_TILE(wq, fqA);

        // stage weight tile kt+2 -> buf0; prefetch wR = tile kt+3; features kt+2 -> fqA
        if (kt + 2 < NCH) {
            if (lane < 56)
                *reinterpret_cast<float4*>(&s_wv[wvid][0][lane * 4]) = wR;
            if (kt + 3 < NCH)
                wR = *reinterpret_cast<const float4*>(w1g + (kt + 3) * 4);
            LD_FQ(fqA, kt + 2);
        }
        __builtin_amdgcn_sched_barrier(0);   // fqA loads stay above FMA(B)
        LD_WQ(wq, 1);
        FMA_TILE(wq, fqB);
    }
    if (NCH & 1) {                   // odd NCH (NF=140): last (even) tile in fqA/buf0
        LD_WQ(wq, 0);
        FMA_TILE(wq, fqA);
    }
#undef FMA_TILE
#undef LD_WQ
#undef LD_FQ
    __syncthreads();                 // all waves done reading U -> overlay H

    // H-write (UH reused as H; U dead).
    const int ng = tid >> 3;
    #pragma unroll
    for (int j = 0; j < 7; j++) {
        const int n = ng * 7 + j;
        if (n < 200) {
            const float bb = b1[n];
            const int n4 = n & ~3, nl = n & 3;
            #pragma unroll
            for (int i = 0; i < 8; i++) {
                const float h = acc[j][i][0] + acc[j][i][1] + bb;
                UH[(rg * 8 + i) * SH + ((n4 ^ (rg * 4)) | nl)] = h > 0.f ? h : 0.f;
            }
        }
    }
    __syncthreads();

    // Phase C: lane = row; wave w handles outputs {w, w+4, w+8} (uniform -> s_load w2).
    const int r = lane;
    {
        const int rx = (r >> 3) * 4;     // lane-varying XOR key
        v2f a2[3];
        #pragma unroll
        for (int m = 0; m < 3; m++) a2[m] = (v2f){0.f, 0.f};
        for (int kc = 0; kc < FFDIM / 4; kc++) {
            const float4 hv = *reinterpret_cast<const float4*>(
                &UH[r * SH + ((kc * 4) ^ rx)]);
            const v2f hlo = (v2f){hv.x, hv.y}, hhi = (v2f){hv.z, hv.w};
            #pragma unroll
            for (int m = 0; m < 3; m++) {
                const int o = wvid + 4 * m;
                if (o < NOUT) {
                    const float4 w2v = *reinterpret_cast<const float4*>(
                        w2 + (size_t)o * FFDIM + kc * 4);
                    a2[m] += (v2f){w2v.x, w2v.y} * hlo;
                    a2[m] += (v2f){w2v.z, w2v.w} * hhi;
                }
            }
        }
        #pragma unroll
        for (int m = 0; m < 3; m++) {
            const int o = wvid + 4 * m;
            if (o < NOUT) s_out[r * SO + o] = a2[m][0] + a2[m][1] + b2[o];
        }
    }
    __syncthreads();

    if (SELECT) {
        if (tid < RB) {              // per-row top-6 (ties -> lowest index), sorted asc
            float sc[10];
            #pragma unroll
            for (int o = 0; o < 10; o++) sc[o] = s_out[tid * SO + o];
            bool used[10];
            #pragma unroll
            for (int o = 0; o < 10; o++) used[o] = false;
            int ids[6];
            for (int k = 0; k < 6; k++) {
                float m = -3.0e38f; int mi = 0;
                for (int o = 0; o < 10; o++)
                    if (!used[o] && sc[o] > m) { m = sc[o]; mi = o; }
                used[mi] = true; ids[k] = mi;
            }
            for (int a2i = 1; a2i < 6; a2i++) {  // insertion sort ascending
                const int v = ids[a2i]; int bp = a2i - 1;
                while (bp >= 0 && ids[bp] > v) { ids[bp + 1] = ids[bp]; bp--; }
                ids[bp + 1] = v;
            }
            #pragma unroll
            for (int k = 0; k < 6; k++) s_idx[tid * 6 + k] = ids[k];
        }
        __syncthreads();
        for (int q = tid; q < RB * 6; q += 256) {    // float4 gather of selected jets
            const int r2 = q / 6, j = q - r2 * 6;
            reinterpret_cast<float4*>(selout)[(size_t)blk * RB * 6 + q] =
                reinterpret_cast<const float4*>(vectors)
                    [(size_t)(blk * RB + r2) * NJ + s_idx[r2 * 6 + j]];
        }
    }

    for (int q = tid; q < RB * NOUT; q += 256) {
        const int r2 = q / NOUT, o = q - r2 * NOUT;
        out[(size_t)(blk * RB + r2) * OUTSTRIDE + out_off + o] = s_out[r2 * SO + o];
    }
}

extern "C" void kernel_launch(void* const* d_in, const int* in_sizes, int n_in,
                              void* d_out, int out_size, void* d_ws, size_t ws_size,
                              hipStream_t stream) {
    const float* vectors  = (const float*)d_in[0];
    const float* isr_cola = (const float*)d_in[1];
    const float* isr_we   = (const float*)d_in[2];
    const float* isr_wd   = (const float*)d_in[3];
    const float* isr_bn_g = (const float*)d_in[4];
    const float* isr_bn_b = (const float*)d_in[5];
    const float* isr_w1   = (const float*)d_in[6];
    const float* isr_b1   = (const float*)d_in[7];
    const float* isr_w2   = (const float*)d_in[8];
    const float* isr_b2   = (const float*)d_in[9];
    const float* dec_cola = (const float*)d_in[10];
    const float* dec_we   = (const float*)d_in[11];
    const float* dec_wd   = (const float*)d_in[12];
    const float* dec_bn_g = (const float*)d_in[13];
    const float* dec_bn_b = (const float*)d_in[14];
    const float* dec_w1   = (const float*)d_in[15];
    const float* dec_b1   = (const float*)d_in[16];
    const float* dec_w2   = (const float*)d_in[17];
    const float* dec_b2   = (const float*)d_in[18];
    float* out = (float*)d_out;
    float* ws  = (float*)d_ws;

    // workspace layout (floats); f_buf reused by both heads (~29.4 MB total)
    float* f_buf  = ws;                    // 32768*160 = 5,242,880
    float* sel    = f_buf + 5242880;       // 32768*24 = 786,432
    float* ps     = sel + 786432;          // 160*4096 = 655,360
    float* pq     = ps + 655360;           // 655,360
    float* bn_i   = pq + 655360;           // 320
    float* bn_d   = bn_i + 320;            // 280

    feat_kernel<10, 32><<<4096, 256, 0, stream>>>(vectors, isr_cola, isr_we, isr_wd,
                                                  f_buf, ps, pq);
    bn_reduce<160><<<160, 256, 0, stream>>>(ps, pq, isr_bn_g, isr_bn_b, bn_i);
    mlp_kernel<160, 10, true><<<512, 256, 0, stream>>>(f_buf, bn_i, isr_w1, isr_b1,
                                                       isr_w2, isr_b2, vectors, sel,
                                                       out, 0);
    feat_kernel<6, 28><<<4096, 256, 0, stream>>>(sel, dec_cola, dec_we, dec_wd,
                                                 f_buf, ps, pq);
    bn_reduce<140><<<140, 256, 0, stream>>>(ps, pq, dec_bn_g, dec_bn_b, bn_d);
    mlp_kernel<140, 11, false><<<512, 256, 0, stream>>>(f_buf, bn_d, dec_w1, dec_b1,
                                                        dec_w2, dec_b2, nullptr, nullptr,
                                                        out, 10);
}